// Round 6
// baseline (335.996 us; speedup 1.0000x reference)
//
#include <hip/hip_runtime.h>
#include <hip/hip_cooperative_groups.h>
#include <math.h>

namespace cg = cooperative_groups;

// Problem constants
#define NB 128     // batch
#define NR 1152    // routes
#define NC 10      // capsules
#define NCHK 24    // partial chunks per capsule (route-chunks of 48)

typedef __attribute__((ext_vector_type(8))) short bf16x8;
typedef __attribute__((ext_vector_type(16))) float f32x16;

__device__ __forceinline__ unsigned pk_bf16(float a, float b) {
    unsigned r;
    asm("v_cvt_pk_bf16_f32 %0, %1, %2" : "=v"(r) : "v"(a), "v"(b));
    return r;
}

// ------------------------------------------------------------------
// pass_phase: on-the-fly bf16x3 + 32x32x16 MFMA pred + route reduction.
// A = W (M=o), B = xT (N=b, coalesced). C: col(l&31)=b, row(reg&3)+8*(reg>>2)+4*hi1=o.
// MODE 0: uniform sum (MFMA-chained). MODE 1: d=pred.ov, e=exp(d-20), Z+=e, acc+=e*pred.
// Tail: 8-wave XOR-swizzled LDS merge -> ps[c][rch][128][32], pz[c][rch][128].
// ------------------------------------------------------------------
template<int MODE>
__device__ __forceinline__ void pass_phase(const float* __restrict__ xT,
                                           const float* __restrict__ W,
                                           int c, int rch, int h, int bp,
                                           int lo5, int hi1, int t, int l,
                                           float (&ov0)[16], float (&ov1)[16],
                                           float* __restrict__ ps,
                                           float* __restrict__ pz,
                                           float* lds)
{
    const int r0 = rch * 48 + h * 12;
    f32x16 acc0, acc1, zz;
#pragma unroll
    for (int j = 0; j < 16; ++j) { acc0[j] = 0.f; acc1[j] = 0.f; zz[j] = 0.f; }
    float Z0 = 0.f, Z1 = 0.f;

    // W element (r, i=hi1*8+j, o=lo5)
    const float* wb = W + ((size_t)(c * NR + r0) * 16 + hi1 * 8) * 32 + lo5;
    // xT float4 units: index ((r*2+hi1)*2 + j4)*128 + b
    const float4* xt0 = (const float4*)xT + ((size_t)(r0 * 2 + hi1) * 2) * 128 + (bp * 64 + lo5);
    const float4* xt1 = xt0 + 32;

#pragma unroll 4
    for (int rr = 0; rr < 12; ++rr) {
        // ---- W fragment: 8 strided f32 -> hi/lo bf16 planes ----
        float wv[8];
#pragma unroll
        for (int j = 0; j < 8; ++j) wv[j] = wb[rr * 512 + j * 32];
        union { unsigned u[4]; bf16x8 v; } Ah, Al, Xh0, Xl0, Xh1, Xl1;
#pragma unroll
        for (int j = 0; j < 4; ++j) Ah.u[j] = pk_bf16(wv[2*j], wv[2*j+1]);
#pragma unroll
        for (int j = 0; j < 4; ++j) {
            float g0 = __uint_as_float(Ah.u[j] << 16);
            float g1 = __uint_as_float(Ah.u[j] & 0xffff0000u);
            Al.u[j] = pk_bf16(wv[2*j] - g0, wv[2*j+1] - g1);
        }
        // ---- x fragments (coalesced via xT) ----
        float4 u0 = xt0[rr * 512];
        float4 u1 = xt0[rr * 512 + 128];
        float4 v0 = xt1[rr * 512];
        float4 v1 = xt1[rr * 512 + 128];
        float xv0[8] = {u0.x,u0.y,u0.z,u0.w, u1.x,u1.y,u1.z,u1.w};
        float xv1[8] = {v0.x,v0.y,v0.z,v0.w, v1.x,v1.y,v1.z,v1.w};
#pragma unroll
        for (int j = 0; j < 4; ++j) Xh0.u[j] = pk_bf16(xv0[2*j], xv0[2*j+1]);
#pragma unroll
        for (int j = 0; j < 4; ++j) {
            float g0 = __uint_as_float(Xh0.u[j] << 16);
            float g1 = __uint_as_float(Xh0.u[j] & 0xffff0000u);
            Xl0.u[j] = pk_bf16(xv0[2*j] - g0, xv0[2*j+1] - g1);
        }
#pragma unroll
        for (int j = 0; j < 4; ++j) Xh1.u[j] = pk_bf16(xv1[2*j], xv1[2*j+1]);
#pragma unroll
        for (int j = 0; j < 4; ++j) {
            float g0 = __uint_as_float(Xh1.u[j] << 16);
            float g1 = __uint_as_float(Xh1.u[j] & 0xffff0000u);
            Xl1.u[j] = pk_bf16(xv1[2*j] - g0, xv1[2*j+1] - g1);
        }

        if (MODE == 0) {
            acc0 = __builtin_amdgcn_mfma_f32_32x32x16_bf16(Ah.v, Xh0.v, acc0, 0, 0, 0);
            acc0 = __builtin_amdgcn_mfma_f32_32x32x16_bf16(Al.v, Xh0.v, acc0, 0, 0, 0);
            acc0 = __builtin_amdgcn_mfma_f32_32x32x16_bf16(Ah.v, Xl0.v, acc0, 0, 0, 0);
            acc1 = __builtin_amdgcn_mfma_f32_32x32x16_bf16(Ah.v, Xh1.v, acc1, 0, 0, 0);
            acc1 = __builtin_amdgcn_mfma_f32_32x32x16_bf16(Al.v, Xh1.v, acc1, 0, 0, 0);
            acc1 = __builtin_amdgcn_mfma_f32_32x32x16_bf16(Ah.v, Xl1.v, acc1, 0, 0, 0);
        } else {
            f32x16 q0, q1;
            q0 = __builtin_amdgcn_mfma_f32_32x32x16_bf16(Ah.v, Xh0.v, zz, 0, 0, 0);
            q1 = __builtin_amdgcn_mfma_f32_32x32x16_bf16(Ah.v, Xh1.v, zz, 0, 0, 0);
            q0 = __builtin_amdgcn_mfma_f32_32x32x16_bf16(Al.v, Xh0.v, q0, 0, 0, 0);
            q1 = __builtin_amdgcn_mfma_f32_32x32x16_bf16(Al.v, Xh1.v, q1, 0, 0, 0);
            q0 = __builtin_amdgcn_mfma_f32_32x32x16_bf16(Ah.v, Xl0.v, q0, 0, 0, 0);
            q1 = __builtin_amdgcn_mfma_f32_32x32x16_bf16(Ah.v, Xl1.v, q1, 0, 0, 0);
            float d0 = 0.f, d1 = 0.f;
#pragma unroll
            for (int j = 0; j < 16; ++j) {
                d0 = fmaf(q0[j], ov0[j], d0);
                d1 = fmaf(q1[j], ov1[j], d1);
            }
            d0 += __shfl_xor(d0, 32);
            d1 += __shfl_xor(d1, 32);
            float e0 = __expf(d0 - 20.0f);
            float e1 = __expf(d1 - 20.0f);
            Z0 += e0; Z1 += e1;
#pragma unroll
            for (int j = 0; j < 16; ++j) {
                acc0[j] = fmaf(e0, q0[j], acc0[j]);
                acc1[j] = fmaf(e1, q1[j], acc1[j]);
            }
        }
    }

    // ---- 8-wave LDS merge (4 h-slices; b-halves disjoint) ----
    const int b0 = bp * 64 + lo5, b1 = b0 + 32;
    __syncthreads();
#pragma unroll
    for (int j = 0; j < 16; ++j) {
        int orow = (j & 3) + 8 * (j >> 2) + 4 * hi1;
        lds[h * 4096 + b0 * 32 + (orow ^ lo5)] = acc0[j];
        lds[h * 4096 + b1 * 32 + (orow ^ lo5)] = acc1[j];
    }
    __syncthreads();
    float* po = ps + (size_t)(c * NCHK + rch) * 4096;
    for (int idx = t; idx < 4096; idx += 512) {
        int b = idx >> 5, o = idx & 31;
        float s = 0.f;
#pragma unroll
        for (int hh = 0; hh < 4; ++hh)
            s += lds[hh * 4096 + b * 32 + (o ^ (b & 31))];
        po[idx] = s;
    }
    if (MODE == 1) {
        __syncthreads();
        if (l < 32) {
            lds[h * 128 + bp * 64 + lo5] = Z0;
            lds[h * 128 + bp * 64 + 32 + lo5] = Z1;
        }
        __syncthreads();
        if (t < 128) {
            float z = lds[t] + lds[128 + t] + lds[256 + t] + lds[384 + t];
            pz[(size_t)(c * NCHK + rch) * 128 + t] = z;
        }
    }
}

// ------------------------------------------------------------------
// merge_phase: every block merges its capsule's 24 chunks, squashes over
// batch in-LDS, and extracts this lane's out-fragments into registers.
// M=0: uniform (s/1152), ov = out. M=1: softmax (s/Z), ov += out.
// M=2: softmax, write dout (gated) only.
// LDS: s[128][33] @0..4224 | zr @4224 | red @4480..5008 | f @5008..5040
// ------------------------------------------------------------------
template<int M>
__device__ __forceinline__ void merge_phase(const float* __restrict__ ps,
                                            const float* __restrict__ pz,
                                            int c, int t, int bp, int lo5, int hi1,
                                            float (&ov0)[16], float (&ov1)[16],
                                            float* __restrict__ dout, bool dowrite,
                                            float* lds)
{
    __syncthreads();
    if (M >= 1) {
        if (t < 128) {
            float z = 0.f;
#pragma unroll
            for (int ch = 0; ch < NCHK; ++ch)
                z += pz[(size_t)(c * NCHK + ch) * 128 + t];
            lds[4224 + t] = z;
        }
        __syncthreads();
    }
    float svloc[8];
    float pn = 0.f;
    const float* pc = ps + (size_t)c * NCHK * 4096;
#pragma unroll
    for (int k = 0; k < 8; ++k) {
        int idx = t + 512 * k;
        float s = 0.f;
#pragma unroll
        for (int ch = 0; ch < NCHK; ++ch) s += pc[ch * 4096 + idx];
        float sv = (M == 0) ? s * (1.0f / 1152.0f) : s / lds[4224 + (idx >> 5)];
        svloc[k] = sv;
        pn = fmaf(sv, sv, pn);
        lds[(idx >> 5) * 33 + (idx & 31)] = sv;
    }
    lds[4480 + (t >> 5) * 33 + (t & 31)] = pn;
    __syncthreads();
    if (t < 32) {
        float n2 = 0.f;
#pragma unroll
        for (int m = 0; m < 16; ++m) n2 += lds[4480 + m * 33 + t];
        lds[5008 + t] = sqrtf(n2) / (1.0f + n2);   // (n2/(1+n2))/sqrt(n2)
    }
    __syncthreads();
    if (M == 2) {
        if (dowrite) {
#pragma unroll
            for (int k = 0; k < 8; ++k) {
                int idx = t + 512 * k;
                dout[(size_t)c * 4096 + idx] = svloc[k] * lds[5008 + (idx & 31)];
            }
        }
    } else {
#pragma unroll
        for (int j = 0; j < 16; ++j) {
            int orow = (j & 3) + 8 * (j >> 2) + 4 * hi1;
            float fo = lds[5008 + orow];
            float v0 = lds[(bp * 64 + lo5) * 33 + orow] * fo;
            float v1 = lds[(bp * 64 + 32 + lo5) * 33 + orow] * fo;
            if (M == 0) { ov0[j] = v0;  ov1[j] = v1; }
            else        { ov0[j] += v0; ov1[j] += v1; }
        }
    }
}

// ------------------------------------------------------------------
// fused_k: ONE cooperative kernel for the whole routing layer.
// 240 blocks x 512 thr. Phases: xT transpose | pass0 | merge | pass1 |
// merge | pass2 | merge+write. 3+1 grid syncs; part_s/pZ double-buffered.
// ------------------------------------------------------------------
__global__ __launch_bounds__(512, 2) void fused_k(const float* __restrict__ x,
                                                  const float* __restrict__ W,
                                                  float* __restrict__ xT,
                                                  float* __restrict__ psA,
                                                  float* __restrict__ psB,
                                                  float* __restrict__ pzA,
                                                  float* __restrict__ pzB,
                                                  float* __restrict__ dout)
{
    cg::grid_group grid = cg::this_grid();
    __shared__ float lds[16384];   // 64 KB

    const int pb = blockIdx.x;
    const int lin = (pb & 7) * 30 + (pb >> 3);   // chunked XCD swizzle (240 = 8*30)
    const int rch = lin / 10;
    const int c   = lin - rch * 10;
    const int t = threadIdx.x;
    const int w = t >> 6, l = t & 63;
    const int h = w >> 1, bp = w & 1;
    const int lo5 = l & 31, hi1 = l >> 5;
    const bool dowrite = (rch == 0);

    // ---- Phase P: transpose x -> xT[((r*2+hi)*2+j4)*128 + b] (float4) ----
    {
        float4* xt4 = (float4*)xT;
        for (int u = pb * 512 + t; u < NB * NR; u += 240 * 512) {
            int b = u / NR, r = u - b * NR;
            const float4* src = (const float4*)(x + (size_t)u * 16 -
                                                (size_t)b * NR * 16 + (size_t)b * NR * 16);
            // src = x + ((size_t)b*NR + r)*16, expressed simply:
            src = (const float4*)(x + ((size_t)b * NR + r) * 16);
#pragma unroll
            for (int j4 = 0; j4 < 4; ++j4) {
                float4 v = src[j4];
                int hi = j4 >> 1, lo = j4 & 1;
                xt4[((size_t)(r * 2 + hi) * 2 + lo) * 128 + b] = v;
            }
        }
    }
    grid.sync();

    float ov0[16], ov1[16];

    // ---- iter 0: uniform ----
    pass_phase<0>(xT, W, c, rch, h, bp, lo5, hi1, t, l, ov0, ov1, psA, pzA, lds);
    grid.sync();
    merge_phase<0>(psA, pzA, c, t, bp, lo5, hi1, ov0, ov1, dout, false, lds);

    // ---- iter 1: softmax(pred . out0) ----
    pass_phase<1>(xT, W, c, rch, h, bp, lo5, hi1, t, l, ov0, ov1, psB, pzB, lds);
    grid.sync();
    merge_phase<1>(psB, pzB, c, t, bp, lo5, hi1, ov0, ov1, dout, false, lds);

    // ---- iter 2: softmax(pred . (out0+out1)) -> dout ----
    pass_phase<1>(xT, W, c, rch, h, bp, lo5, hi1, t, l, ov0, ov1, psA, pzA, lds);
    grid.sync();
    merge_phase<2>(psA, pzA, c, t, bp, lo5, hi1, ov0, ov1, dout, dowrite, lds);
}

// ------------------------------------------------------------------
// LEGACY FALLBACK: round-5 multi-launch path (used if cooperative
// launch is rejected, e.g. by graph capture).
// ------------------------------------------------------------------
template<int MODE>
__global__ __launch_bounds__(512, 2) void pass_g(const float* __restrict__ x,
                                                 const float* __restrict__ W,
                                                 const float* __restrict__ oacc,
                                                 float* __restrict__ part_s,
                                                 float* __restrict__ pZ)
{
    __shared__ float lds[16384];
    const int pb = blockIdx.x;
    const int lin = (pb & 7) * 30 + (pb >> 3);
    const int rch = lin / 10;
    const int c   = lin - rch * 10;
    const int t = threadIdx.x;
    const int w = t >> 6, l = t & 63;
    const int h = w >> 1, bp = w & 1;
    const int lo5 = l & 31, hi1 = l >> 5;
    const int r0 = rch * 48 + h * 12;

    if (MODE == 1) {
        const float* ob = oacc + (size_t)c * NB * 32;
        for (int idx = t; idx < 4096; idx += 512)
            lds[(idx >> 5) * 33 + (idx & 31)] = ob[idx];
    }
    __syncthreads();

    float ov0[16], ov1[16];
    if (MODE == 1) {
#pragma unroll
        for (int j = 0; j < 16; ++j) {
            int orow = (j & 3) + 8 * (j >> 2) + 4 * hi1;
            ov0[j] = lds[(bp * 64 + lo5) * 33 + orow];
            ov1[j] = lds[(bp * 64 + 32 + lo5) * 33 + orow];
        }
    }

    f32x16 acc0, acc1, zz;
#pragma unroll
    for (int j = 0; j < 16; ++j) { acc0[j] = 0.f; acc1[j] = 0.f; zz[j] = 0.f; }
    float Z0 = 0.f, Z1 = 0.f;

    const float* wb  = W + ((size_t)(c * NR + r0) * 16 + hi1 * 8) * 32 + lo5;
    const float* xp0 = x + ((size_t)(bp * 64 + lo5) * NR + r0) * 16 + hi1 * 8;
    const float* xp1 = x + ((size_t)(bp * 64 + 32 + lo5) * NR + r0) * 16 + hi1 * 8;

    for (int rr = 0; rr < 12; ++rr) {
        float wv[8];
#pragma unroll
        for (int j = 0; j < 8; ++j) wv[j] = wb[(size_t)rr * 512 + j * 32];
        union { unsigned u[4]; bf16x8 v; } Ah, Al, Xh0, Xl0, Xh1, Xl1;
#pragma unroll
        for (int j = 0; j < 4; ++j) Ah.u[j] = pk_bf16(wv[2*j], wv[2*j+1]);
#pragma unroll
        for (int j = 0; j < 4; ++j) {
            float g0 = __uint_as_float(Ah.u[j] << 16);
            float g1 = __uint_as_float(Ah.u[j] & 0xffff0000u);
            Al.u[j] = pk_bf16(wv[2*j] - g0, wv[2*j+1] - g1);
        }
        float4 u0 = *(const float4*)(xp0 + rr * 16);
        float4 u1 = *(const float4*)(xp0 + rr * 16 + 4);
        float xv0[8] = {u0.x,u0.y,u0.z,u0.w, u1.x,u1.y,u1.z,u1.w};
#pragma unroll
        for (int j = 0; j < 4; ++j) Xh0.u[j] = pk_bf16(xv0[2*j], xv0[2*j+1]);
#pragma unroll
        for (int j = 0; j < 4; ++j) {
            float g0 = __uint_as_float(Xh0.u[j] << 16);
            float g1 = __uint_as_float(Xh0.u[j] & 0xffff0000u);
            Xl0.u[j] = pk_bf16(xv0[2*j] - g0, xv0[2*j+1] - g1);
        }
        float4 v0 = *(const float4*)(xp1 + rr * 16);
        float4 v1 = *(const float4*)(xp1 + rr * 16 + 4);
        float xv1[8] = {v0.x,v0.y,v0.z,v0.w, v1.x,v1.y,v1.z,v1.w};
#pragma unroll
        for (int j = 0; j < 4; ++j) Xh1.u[j] = pk_bf16(xv1[2*j], xv1[2*j+1]);
#pragma unroll
        for (int j = 0; j < 4; ++j) {
            float g0 = __uint_as_float(Xh1.u[j] << 16);
            float g1 = __uint_as_float(Xh1.u[j] & 0xffff0000u);
            Xl1.u[j] = pk_bf16(xv1[2*j] - g0, xv1[2*j+1] - g1);
        }

        if (MODE == 0) {
            acc0 = __builtin_amdgcn_mfma_f32_32x32x16_bf16(Ah.v, Xh0.v, acc0, 0, 0, 0);
            acc0 = __builtin_amdgcn_mfma_f32_32x32x16_bf16(Al.v, Xh0.v, acc0, 0, 0, 0);
            acc0 = __builtin_amdgcn_mfma_f32_32x32x16_bf16(Ah.v, Xl0.v, acc0, 0, 0, 0);
            acc1 = __builtin_amdgcn_mfma_f32_32x32x16_bf16(Ah.v, Xh1.v, acc1, 0, 0, 0);
            acc1 = __builtin_amdgcn_mfma_f32_32x32x16_bf16(Al.v, Xh1.v, acc1, 0, 0, 0);
            acc1 = __builtin_amdgcn_mfma_f32_32x32x16_bf16(Ah.v, Xl1.v, acc1, 0, 0, 0);
        } else {
            f32x16 q0, q1;
            q0 = __builtin_amdgcn_mfma_f32_32x32x16_bf16(Ah.v, Xh0.v, zz, 0, 0, 0);
            q1 = __builtin_amdgcn_mfma_f32_32x32x16_bf16(Ah.v, Xh1.v, zz, 0, 0, 0);
            q0 = __builtin_amdgcn_mfma_f32_32x32x16_bf16(Al.v, Xh0.v, q0, 0, 0, 0);
            q1 = __builtin_amdgcn_mfma_f32_32x32x16_bf16(Al.v, Xh1.v, q1, 0, 0, 0);
            q0 = __builtin_amdgcn_mfma_f32_32x32x16_bf16(Ah.v, Xl0.v, q0, 0, 0, 0);
            q1 = __builtin_amdgcn_mfma_f32_32x32x16_bf16(Ah.v, Xl1.v, q1, 0, 0, 0);
            float d0 = 0.f, d1 = 0.f;
#pragma unroll
            for (int j = 0; j < 16; ++j) {
                d0 = fmaf(q0[j], ov0[j], d0);
                d1 = fmaf(q1[j], ov1[j], d1);
            }
            d0 += __shfl_xor(d0, 32);
            d1 += __shfl_xor(d1, 32);
            float e0 = __expf(d0 - 20.0f);
            float e1 = __expf(d1 - 20.0f);
            Z0 += e0; Z1 += e1;
#pragma unroll
            for (int j = 0; j < 16; ++j) {
                acc0[j] = fmaf(e0, q0[j], acc0[j]);
                acc1[j] = fmaf(e1, q1[j], acc1[j]);
            }
        }
    }

    const int b0 = bp * 64 + lo5, b1 = b0 + 32;
    __syncthreads();
#pragma unroll
    for (int j = 0; j < 16; ++j) {
        int orow = (j & 3) + 8 * (j >> 2) + 4 * hi1;
        lds[h * 4096 + b0 * 32 + (orow ^ lo5)] = acc0[j];
        lds[h * 4096 + b1 * 32 + (orow ^ lo5)] = acc1[j];
    }
    __syncthreads();
    float* po = part_s + (size_t)(c * NCHK + rch) * 4096;
    for (int idx = t; idx < 4096; idx += 512) {
        int b = idx >> 5, o = idx & 31;
        float s = 0.f;
#pragma unroll
        for (int hh = 0; hh < 4; ++hh)
            s += lds[hh * 4096 + b * 32 + (o ^ (b & 31))];
        po[idx] = s;
    }
    if (MODE == 1) {
        __syncthreads();
        if (l < 32) {
            lds[h * 128 + bp * 64 + lo5] = Z0;
            lds[h * 128 + bp * 64 + 32 + lo5] = Z1;
        }
        __syncthreads();
        if (t < 128) {
            float z = lds[t] + lds[128 + t] + lds[256 + t] + lds[384 + t];
            pZ[(size_t)(c * NCHK + rch) * 128 + t] = z;
        }
    }
}

template<int MODE>
__global__ __launch_bounds__(256) void msq_k(const float* __restrict__ part_s,
                                             const float* __restrict__ pZ,
                                             float* __restrict__ oacc,
                                             float* __restrict__ dout)
{
    const int c = blockIdx.x, og = blockIdx.y;
    const int t = threadIdx.x;
    const int o_off = t & 7, b_lo = t >> 3;
    const int o = og * 8 + o_off;

    float sv[4];
    float pn = 0.f;
#pragma unroll
    for (int k = 0; k < 4; ++k) {
        int bb = b_lo + 32 * k;
        float s = 0.f;
#pragma unroll
        for (int ch = 0; ch < NCHK; ++ch)
            s += part_s[(((size_t)c * NCHK + ch) * NB + bb) * 32 + o];
        if (MODE == 0) {
            sv[k] = s * (1.0f / 1152.0f);
        } else {
            float z = 0.f;
#pragma unroll
            for (int ch = 0; ch < NCHK; ++ch)
                z += pZ[((size_t)c * NCHK + ch) * NB + bb];
            sv[k] = s / z;
        }
        pn = fmaf(sv[k], sv[k], pn);
    }
    __shared__ float red[256];
    __shared__ float fsh[8];
    red[t] = pn;
    __syncthreads();
    if (t < 8) {
        float n2 = 0.f;
#pragma unroll
        for (int j = 0; j < 32; ++j) n2 += red[t + 8 * j];
        fsh[t] = sqrtf(n2) / (1.0f + n2);
    }
    __syncthreads();
    float f = fsh[o_off];
#pragma unroll
    for (int k = 0; k < 4; ++k) {
        int bb = b_lo + 32 * k;
        float v = sv[k] * f;
        size_t idx = ((size_t)c * NB + bb) * 32 + o;
        if (MODE == 0) oacc[idx] = v;
        if (MODE == 1) oacc[idx] += v;
        if (MODE == 2) dout[idx] = v;
    }
}

// ------------------------------------------------------------------
extern "C" void kernel_launch(void* const* d_in, const int* in_sizes, int n_in,
                              void* d_out, int out_size, void* d_ws, size_t ws_size,
                              hipStream_t stream)
{
    (void)in_sizes; (void)n_in; (void)out_size; (void)ws_size;
    const float* x = (const float*)d_in[0];
    const float* W = (const float*)d_in[1];
    float* wsf  = (float*)d_ws;
    float* outf = (float*)d_out;

    // ws layout (float units):
    // xT 2,359,296 | psA 983,040 | psB 983,040 | pzA 30,720 | pzB 30,720 | oacc 40,960
    float* xT  = wsf;
    float* psA = xT  + (size_t)NR * 2 * 2 * 128 * 4;
    float* psB = psA + (size_t)NC * NCHK * NB * 32;
    float* pzA = psB + (size_t)NC * NCHK * NB * 32;
    float* pzB = pzA + (size_t)NC * NCHK * NB;
    float* oacc = pzB + (size_t)NC * NCHK * NB;

    void* args[] = { (void*)&x, (void*)&W, (void*)&xT, (void*)&psA, (void*)&psB,
                     (void*)&pzA, (void*)&pzB, (void*)&outf };
    hipError_t e = hipLaunchCooperativeKernel((const void*)fused_k,
                                              dim3(240), dim3(512),
                                              args, 0, stream);
    if (e != hipSuccess) {
        // Fallback: round-5 proven multi-launch path.
        dim3 mg(NC, 4);
        pass_g<0><<<240, 512, 0, stream>>>(x, W, nullptr, psA, pzA);
        msq_k<0><<<mg, 256, 0, stream>>>(psA, pzA, oacc, nullptr);
        pass_g<1><<<240, 512, 0, stream>>>(x, W, oacc, psA, pzA);
        msq_k<1><<<mg, 256, 0, stream>>>(psA, pzA, oacc, nullptr);
        pass_g<1><<<240, 512, 0, stream>>>(x, W, oacc, psA, pzA);
        msq_k<2><<<mg, 256, 0, stream>>>(psA, pzA, oacc, outf);
    }
}

// Round 7
// 91.555 us; speedup vs baseline: 3.6699x; 3.6699x over previous
//
#include <hip/hip_runtime.h>
#include <math.h>

// Problem constants
#define NB 128     // batch
#define NR 1152    // routes
#define NC 10      // capsules
#define NCHK 48    // partial chunks per capsule (route-chunks of 24)

typedef __attribute__((ext_vector_type(8))) short bf16x8;
typedef __attribute__((ext_vector_type(16))) float f32x16;

__device__ __forceinline__ unsigned pk_bf16(float a, float b) {
    unsigned r;
    asm("v_cvt_pk_bf16_f32 %0, %1, %2" : "=v"(r) : "v"(a), "v"(b));
    return r;
}

// ------------------------------------------------------------------
// pass_h: fused on-the-fly bf16x3 conversion + 32x32x16 MFMA pred +
// (uniform | softmax-weighted) route reduction.
// Grid 480 = (10 c x 48 rch of 24 routes), XCD-chunked: XCD k owns
// rch [6k,6k+6) x all c -> x slice 1.2 MB + W slice 2.9 MB L2-resident.
// 512 thr = 8 waves: wave = (h = route-sixth of 6, bp = batch-half).
// A = W (M=o), B = x (N=b). C: col(l&31)=b, row(reg&3)+8*(reg>>2)+4*hi1=o.
// MODE 0: uniform sum, x read direct (scattered); c==0 blocks also write
//         coalesced xT (free transpose side-effect).
// MODE 1: x read from xT (coalesced); d = pred.ov, e = exp(d-20), Z += e,
//         acc += e*pred.
// Tail: 8-wave XOR-swizzled LDS merge -> ps[c][rch][128][32], pz[...][128].
// ------------------------------------------------------------------
template<int MODE>
__global__ __launch_bounds__(512, 2) void pass_h(const float* __restrict__ x,
                                                 const float* __restrict__ W,
                                                 float* __restrict__ xT,
                                                 const float* __restrict__ oacc,
                                                 float* __restrict__ ps,
                                                 float* __restrict__ pz)
{
    __shared__ float lds[16384];   // 64 KB: oacc stage / 4-slice merge
    const int pb = blockIdx.x;
    const int lin = (pb & 7) * 60 + (pb >> 3);   // chunked XCD swizzle (480 = 8*60)
    const int rch = lin / 10;
    const int c   = lin - rch * 10;
    const int t = threadIdx.x;
    const int w = t >> 6, l = t & 63;
    const int h = w >> 1, bp = w & 1;
    const int lo5 = l & 31, hi1 = l >> 5;
    const int r0 = rch * 24 + h * 6;

    if (MODE == 1) {
        const float* ob = oacc + (size_t)c * NB * 32;
        for (int idx = t; idx < 4096; idx += 512)
            lds[(idx >> 5) * 33 + (idx & 31)] = ob[idx];
    }
    __syncthreads();

    float ov0[16], ov1[16];
    if (MODE == 1) {
#pragma unroll
        for (int j = 0; j < 16; ++j) {
            int orow = (j & 3) + 8 * (j >> 2) + 4 * hi1;
            ov0[j] = lds[(bp * 64 + lo5) * 33 + orow];
            ov1[j] = lds[(bp * 64 + 32 + lo5) * 33 + orow];
        }
    }

    f32x16 acc0, acc1, zz;
#pragma unroll
    for (int j = 0; j < 16; ++j) { acc0[j] = 0.f; acc1[j] = 0.f; zz[j] = 0.f; }
    float Z0 = 0.f, Z1 = 0.f;

    // W element (r, i=hi1*8+j, o=lo5)
    const float* wb = W + ((size_t)(c * NR + r0) * 16 + hi1 * 8) * 32 + lo5;
    // direct-x pointers (MODE 0)
    const float* xp0 = x + ((size_t)(bp * 64 + lo5) * NR + r0) * 16 + hi1 * 8;
    const float* xp1 = x + ((size_t)(bp * 64 + 32 + lo5) * NR + r0) * 16 + hi1 * 8;
    // xT pointers (float4 units): index ((r*2+hi1)*2 + j4)*128 + b
    float4*       xt4 = (float4*)xT;
    const float4* xt0 = (const float4*)xT + ((size_t)(r0 * 2 + hi1) * 2) * 128 + (bp * 64 + lo5);
    const float4* xt1 = xt0 + 32;
    const bool wrx = (MODE == 0) && (c == 0);

#pragma unroll
    for (int rr = 0; rr < 6; ++rr) {
        // ---- W fragment: 8 strided f32 -> hi/lo bf16 planes ----
        float wv[8];
#pragma unroll
        for (int j = 0; j < 8; ++j) wv[j] = wb[rr * 512 + j * 32];
        union { unsigned u[4]; bf16x8 v; } Ah, Al, Xh0, Xl0, Xh1, Xl1;
#pragma unroll
        for (int j = 0; j < 4; ++j) Ah.u[j] = pk_bf16(wv[2*j], wv[2*j+1]);
#pragma unroll
        for (int j = 0; j < 4; ++j) {
            float g0 = __uint_as_float(Ah.u[j] << 16);
            float g1 = __uint_as_float(Ah.u[j] & 0xffff0000u);
            Al.u[j] = pk_bf16(wv[2*j] - g0, wv[2*j+1] - g1);
        }
        // ---- x fragments ----
        float4 u0, u1, v0, v1;
        if (MODE == 0) {
            u0 = *(const float4*)(xp0 + rr * 16);
            u1 = *(const float4*)(xp0 + rr * 16 + 4);
            v0 = *(const float4*)(xp1 + rr * 16);
            v1 = *(const float4*)(xp1 + rr * 16 + 4);
            if (wrx) {
                size_t base = ((size_t)((r0 + rr) * 2 + hi1) * 2) * 128;
                xt4[base + (bp * 64 + lo5)]            = u0;
                xt4[base + 128 + (bp * 64 + lo5)]      = u1;
                xt4[base + (bp * 64 + 32 + lo5)]       = v0;
                xt4[base + 128 + (bp * 64 + 32 + lo5)] = v1;
            }
        } else {
            u0 = xt0[rr * 512];
            u1 = xt0[rr * 512 + 128];
            v0 = xt1[rr * 512];
            v1 = xt1[rr * 512 + 128];
        }
        float xv0[8] = {u0.x,u0.y,u0.z,u0.w, u1.x,u1.y,u1.z,u1.w};
        float xv1[8] = {v0.x,v0.y,v0.z,v0.w, v1.x,v1.y,v1.z,v1.w};
#pragma unroll
        for (int j = 0; j < 4; ++j) Xh0.u[j] = pk_bf16(xv0[2*j], xv0[2*j+1]);
#pragma unroll
        for (int j = 0; j < 4; ++j) {
            float g0 = __uint_as_float(Xh0.u[j] << 16);
            float g1 = __uint_as_float(Xh0.u[j] & 0xffff0000u);
            Xl0.u[j] = pk_bf16(xv0[2*j] - g0, xv0[2*j+1] - g1);
        }
#pragma unroll
        for (int j = 0; j < 4; ++j) Xh1.u[j] = pk_bf16(xv1[2*j], xv1[2*j+1]);
#pragma unroll
        for (int j = 0; j < 4; ++j) {
            float g0 = __uint_as_float(Xh1.u[j] << 16);
            float g1 = __uint_as_float(Xh1.u[j] & 0xffff0000u);
            Xl1.u[j] = pk_bf16(xv1[2*j] - g0, xv1[2*j+1] - g1);
        }

        if (MODE == 0) {
            acc0 = __builtin_amdgcn_mfma_f32_32x32x16_bf16(Ah.v, Xh0.v, acc0, 0, 0, 0);
            acc0 = __builtin_amdgcn_mfma_f32_32x32x16_bf16(Al.v, Xh0.v, acc0, 0, 0, 0);
            acc0 = __builtin_amdgcn_mfma_f32_32x32x16_bf16(Ah.v, Xl0.v, acc0, 0, 0, 0);
            acc1 = __builtin_amdgcn_mfma_f32_32x32x16_bf16(Ah.v, Xh1.v, acc1, 0, 0, 0);
            acc1 = __builtin_amdgcn_mfma_f32_32x32x16_bf16(Al.v, Xh1.v, acc1, 0, 0, 0);
            acc1 = __builtin_amdgcn_mfma_f32_32x32x16_bf16(Ah.v, Xl1.v, acc1, 0, 0, 0);
        } else {
            f32x16 q0, q1;
            q0 = __builtin_amdgcn_mfma_f32_32x32x16_bf16(Ah.v, Xh0.v, zz, 0, 0, 0);
            q1 = __builtin_amdgcn_mfma_f32_32x32x16_bf16(Ah.v, Xh1.v, zz, 0, 0, 0);
            q0 = __builtin_amdgcn_mfma_f32_32x32x16_bf16(Al.v, Xh0.v, q0, 0, 0, 0);
            q1 = __builtin_amdgcn_mfma_f32_32x32x16_bf16(Al.v, Xh1.v, q1, 0, 0, 0);
            q0 = __builtin_amdgcn_mfma_f32_32x32x16_bf16(Ah.v, Xl0.v, q0, 0, 0, 0);
            q1 = __builtin_amdgcn_mfma_f32_32x32x16_bf16(Ah.v, Xl1.v, q1, 0, 0, 0);
            float d0 = 0.f, d1 = 0.f;
#pragma unroll
            for (int j = 0; j < 16; ++j) {
                d0 = fmaf(q0[j], ov0[j], d0);
                d1 = fmaf(q1[j], ov1[j], d1);
            }
            d0 += __shfl_xor(d0, 32);
            d1 += __shfl_xor(d1, 32);
            float e0 = __expf(d0 - 20.0f);
            float e1 = __expf(d1 - 20.0f);
            Z0 += e0; Z1 += e1;
#pragma unroll
            for (int j = 0; j < 16; ++j) {
                acc0[j] = fmaf(e0, q0[j], acc0[j]);
                acc1[j] = fmaf(e1, q1[j], acc1[j]);
            }
        }
    }

    // ---- 8-wave LDS merge (4 h-slices; b-halves disjoint) ----
    const int b0 = bp * 64 + lo5, b1 = b0 + 32;
    __syncthreads();
#pragma unroll
    for (int j = 0; j < 16; ++j) {
        int orow = (j & 3) + 8 * (j >> 2) + 4 * hi1;
        lds[h * 4096 + b0 * 32 + (orow ^ lo5)] = acc0[j];
        lds[h * 4096 + b1 * 32 + (orow ^ lo5)] = acc1[j];
    }
    __syncthreads();
    float* po = ps + (size_t)(c * NCHK + rch) * 4096;
    for (int idx = t; idx < 4096; idx += 512) {
        int b = idx >> 5, o = idx & 31;
        float s = 0.f;
#pragma unroll
        for (int hh = 0; hh < 4; ++hh)
            s += lds[hh * 4096 + b * 32 + (o ^ (b & 31))];
        po[idx] = s;
    }
    if (MODE == 1) {
        __syncthreads();
        if (l < 32) {
            lds[h * 128 + bp * 64 + lo5] = Z0;
            lds[h * 128 + bp * 64 + 32 + lo5] = Z1;
        }
        __syncthreads();
        if (t < 128) {
            float z = lds[t] + lds[128 + t] + lds[256 + t] + lds[384 + t];
            pz[(size_t)(c * NCHK + rch) * 128 + t] = z;
        }
    }
}

// ------------------------------------------------------------------
// msq: merge chunk partials -> s, squash over batch, update oacc / out.
// MODE 0: uniform (s = sum/1152), oacc = squash. 1: oacc += squash. 2: out.
// Grid (10 c, 4 o-groups), 256 thr: t = o_off(8) x b_lo(32)
// ------------------------------------------------------------------
template<int MODE>
__global__ __launch_bounds__(256) void msq_k(const float* __restrict__ part_s,
                                             const float* __restrict__ pZ,
                                             float* __restrict__ oacc,
                                             float* __restrict__ dout)
{
    const int c = blockIdx.x, og = blockIdx.y;
    const int t = threadIdx.x;
    const int o_off = t & 7, b_lo = t >> 3;
    const int o = og * 8 + o_off;

    float sv[4];
    float pn = 0.f;
#pragma unroll
    for (int k = 0; k < 4; ++k) {
        int bb = b_lo + 32 * k;
        float s = 0.f;
#pragma unroll
        for (int ch = 0; ch < NCHK; ++ch)
            s += part_s[(((size_t)c * NCHK + ch) * NB + bb) * 32 + o];
        if (MODE == 0) {
            sv[k] = s * (1.0f / 1152.0f);
        } else {
            float z = 0.f;
#pragma unroll
            for (int ch = 0; ch < NCHK; ++ch)
                z += pZ[((size_t)c * NCHK + ch) * NB + bb];
            sv[k] = s / z;
        }
        pn = fmaf(sv[k], sv[k], pn);
    }
    __shared__ float red[256];
    __shared__ float fsh[8];
    red[t] = pn;
    __syncthreads();
    if (t < 8) {
        float n2 = 0.f;
#pragma unroll
        for (int j = 0; j < 32; ++j) n2 += red[t + 8 * j];
        fsh[t] = sqrtf(n2) / (1.0f + n2);   // (n2/(1+n2))/sqrt(n2)
    }
    __syncthreads();
    float f = fsh[o_off];
#pragma unroll
    for (int k = 0; k < 4; ++k) {
        int bb = b_lo + 32 * k;
        float v = sv[k] * f;
        size_t idx = ((size_t)c * NB + bb) * 32 + o;
        if (MODE == 0) oacc[idx] = v;
        if (MODE == 1) oacc[idx] += v;
        if (MODE == 2) dout[idx] = v;
    }
}

// ------------------------------------------------------------------
extern "C" void kernel_launch(void* const* d_in, const int* in_sizes, int n_in,
                              void* d_out, int out_size, void* d_ws, size_t ws_size,
                              hipStream_t stream)
{
    (void)in_sizes; (void)n_in; (void)out_size; (void)ws_size;
    const float* x = (const float*)d_in[0];
    const float* W = (const float*)d_in[1];
    float* wsf  = (float*)d_ws;
    float* outf = (float*)d_out;

    // ws layout (float units):
    // xT 2,359,296 | ps 1,966,080 | pz 61,440 | oacc 40,960  (~17.7 MB total)
    float* xT   = wsf;
    float* ps   = xT + (size_t)NR * 16 * NB;
    float* pz   = ps + (size_t)NC * NCHK * NB * 32;
    float* oacc = pz + (size_t)NC * NCHK * NB;

    dim3 mg(NC, 4);
    // iter 0: uniform weights; c==0 blocks emit coalesced xT as side-effect
    pass_h<0><<<480, 512, 0, stream>>>(x, W, xT, nullptr, ps, pz);
    msq_k<0><<<mg, 256, 0, stream>>>(ps, pz, oacc, nullptr);
    // iter 1: softmax(pred . out0), coalesced xT reads
    pass_h<1><<<480, 512, 0, stream>>>(x, W, xT, oacc, ps, pz);
    msq_k<1><<<mg, 256, 0, stream>>>(ps, pz, oacc, nullptr);
    // iter 2: softmax(pred . (out0+out1)) -> d_out
    pass_h<1><<<480, 512, 0, stream>>>(x, W, xT, oacc, ps, pz);
    msq_k<2><<<mg, 256, 0, stream>>>(ps, pz, oacc, outf);
}

// Round 8
// 70.236 us; speedup vs baseline: 4.7838x; 1.3035x over previous
//
#include <hip/hip_runtime.h>
#include <math.h>

// Problem constants
#define NB 128     // batch
#define NR 1152    // routes
#define NC 10      // capsules
#define NCHK 24    // partial chunks per capsule (route-chunks of 48)

typedef __attribute__((ext_vector_type(8))) short bf16x8;
typedef __attribute__((ext_vector_type(16))) float f32x16;

__device__ __forceinline__ unsigned pk_bf16(float a, float b) {
    unsigned r;
    asm("v_cvt_pk_bf16_f32 %0, %1, %2" : "=v"(r) : "v"(a), "v"(b));
    return r;
}

// ------------------------------------------------------------------
// pass_x: fused on-the-fly bf16x3 conversion + 32x32x16 MFMA pred +
// (uniform | softmax-weighted) route reduction.  ROUND-5 STRUCTURE.
// Grid 240 = (10 c x 24 rch of 48 routes), XCD-chunked: XCD k owns
// rch [3k,3k+3) x all c -> x slice 2.4 MB + W slice ~2.9 MB L2-resident.
// 512 thr = 8 waves: wave = (h = route-quarter of 12, bp = batch-half).
// A = W (M=o), B = x (N=b). C: col(l&31)=b, row(reg&3)+8*(reg>>2)+4*hi1=o.
// MODE 0: uniform sum (MFMA-chained); x read direct (scattered); each
//         block also writes xT rows of its chunk with (route%10)==c
//         (~5 routes, 512B-coalesced, evenly spread -> no stragglers).
// MODE 1: x read from xT (coalesced 512B/wave); d = pred.ov,
//         e = exp(d-20), Z += e, acc += e*pred.
// Tail: 8-wave XOR-swizzled LDS merge -> ps[c][rch][128][32], pz[...][128].
// ------------------------------------------------------------------
template<int MODE>
__global__ __launch_bounds__(512, 2) void pass_x(const float* __restrict__ x,
                                                 const float* __restrict__ W,
                                                 float* __restrict__ xT,
                                                 const float* __restrict__ oacc,
                                                 float* __restrict__ ps,
                                                 float* __restrict__ pz)
{
    __shared__ float lds[16384];   // 64 KB: oacc stage / 4-slice merge
    const int pb = blockIdx.x;
    const int lin = (pb & 7) * 30 + (pb >> 3);   // chunked XCD swizzle (240 = 8*30)
    const int rch = lin / 10;
    const int c   = lin - rch * 10;
    const int t = threadIdx.x;
    const int w = t >> 6, l = t & 63;
    const int h = w >> 1, bp = w & 1;
    const int lo5 = l & 31, hi1 = l >> 5;
    const int r0 = rch * 48 + h * 12;

    if (MODE == 1) {
        const float* ob = oacc + (size_t)c * NB * 32;
        for (int idx = t; idx < 4096; idx += 512)
            lds[(idx >> 5) * 33 + (idx & 31)] = ob[idx];
    }
    __syncthreads();

    float ov0[16], ov1[16];
    if (MODE == 1) {
#pragma unroll
        for (int j = 0; j < 16; ++j) {
            int orow = (j & 3) + 8 * (j >> 2) + 4 * hi1;
            ov0[j] = lds[(bp * 64 + lo5) * 33 + orow];
            ov1[j] = lds[(bp * 64 + 32 + lo5) * 33 + orow];
        }
    }

    f32x16 acc0, acc1, zz;
#pragma unroll
    for (int j = 0; j < 16; ++j) { acc0[j] = 0.f; acc1[j] = 0.f; zz[j] = 0.f; }
    float Z0 = 0.f, Z1 = 0.f;

    // W element (r, i=hi1*8+j, o=lo5)
    const float* wb  = W + ((size_t)(c * NR + r0) * 16 + hi1 * 8) * 32 + lo5;
    // direct-x pointers (MODE 0)
    const float* xp0 = x + ((size_t)(bp * 64 + lo5) * NR + r0) * 16 + hi1 * 8;
    const float* xp1 = x + ((size_t)(bp * 64 + 32 + lo5) * NR + r0) * 16 + hi1 * 8;
    // xT float4-unit addressing: ((r*2+hi1)*2 + lo)*128 + b
    float4* xt4 = (float4*)xT;
    const int bq0 = bp * 64 + lo5, bq1 = bq0 + 32;

    for (int rr = 0; rr < 12; ++rr) {
        // ---- W fragment: 8 coalesced-by-lane f32 -> hi/lo bf16 planes ----
        float wv[8];
#pragma unroll
        for (int j = 0; j < 8; ++j) wv[j] = wb[(size_t)rr * 512 + j * 32];
        union { unsigned u[4]; bf16x8 v; } Ah, Al, Xh0, Xl0, Xh1, Xl1;
#pragma unroll
        for (int j = 0; j < 4; ++j) Ah.u[j] = pk_bf16(wv[2*j], wv[2*j+1]);
#pragma unroll
        for (int j = 0; j < 4; ++j) {
            float g0 = __uint_as_float(Ah.u[j] << 16);
            float g1 = __uint_as_float(Ah.u[j] & 0xffff0000u);
            Al.u[j] = pk_bf16(wv[2*j] - g0, wv[2*j+1] - g1);
        }
        // ---- x fragments ----
        float4 u0, u1, v0, v1;
        const size_t base4 = ((size_t)((r0 + rr) * 2 + hi1) * 2) * 128;
        if (MODE == 0) {
            u0 = *(const float4*)(xp0 + rr * 16);
            u1 = *(const float4*)(xp0 + rr * 16 + 4);
            v0 = *(const float4*)(xp1 + rr * 16);
            v1 = *(const float4*)(xp1 + rr * 16 + 4);
            // distributed xT write: this block owns routes (h*12+rr)%10 == c
            if (((h * 12 + rr) % 10) == c) {
                xt4[base4 + bq0]       = u0;
                xt4[base4 + 128 + bq0] = u1;
                xt4[base4 + bq1]       = v0;
                xt4[base4 + 128 + bq1] = v1;
            }
        } else {
            u0 = xt4[base4 + bq0];
            u1 = xt4[base4 + 128 + bq0];
            v0 = xt4[base4 + bq1];
            v1 = xt4[base4 + 128 + bq1];
        }
        float xv0[8] = {u0.x,u0.y,u0.z,u0.w, u1.x,u1.y,u1.z,u1.w};
        float xv1[8] = {v0.x,v0.y,v0.z,v0.w, v1.x,v1.y,v1.z,v1.w};
#pragma unroll
        for (int j = 0; j < 4; ++j) Xh0.u[j] = pk_bf16(xv0[2*j], xv0[2*j+1]);
#pragma unroll
        for (int j = 0; j < 4; ++j) {
            float g0 = __uint_as_float(Xh0.u[j] << 16);
            float g1 = __uint_as_float(Xh0.u[j] & 0xffff0000u);
            Xl0.u[j] = pk_bf16(xv0[2*j] - g0, xv0[2*j+1] - g1);
        }
#pragma unroll
        for (int j = 0; j < 4; ++j) Xh1.u[j] = pk_bf16(xv1[2*j], xv1[2*j+1]);
#pragma unroll
        for (int j = 0; j < 4; ++j) {
            float g0 = __uint_as_float(Xh1.u[j] << 16);
            float g1 = __uint_as_float(Xh1.u[j] & 0xffff0000u);
            Xl1.u[j] = pk_bf16(xv1[2*j] - g0, xv1[2*j+1] - g1);
        }

        if (MODE == 0) {
            acc0 = __builtin_amdgcn_mfma_f32_32x32x16_bf16(Ah.v, Xh0.v, acc0, 0, 0, 0);
            acc0 = __builtin_amdgcn_mfma_f32_32x32x16_bf16(Al.v, Xh0.v, acc0, 0, 0, 0);
            acc0 = __builtin_amdgcn_mfma_f32_32x32x16_bf16(Ah.v, Xl0.v, acc0, 0, 0, 0);
            acc1 = __builtin_amdgcn_mfma_f32_32x32x16_bf16(Ah.v, Xh1.v, acc1, 0, 0, 0);
            acc1 = __builtin_amdgcn_mfma_f32_32x32x16_bf16(Al.v, Xh1.v, acc1, 0, 0, 0);
            acc1 = __builtin_amdgcn_mfma_f32_32x32x16_bf16(Ah.v, Xl1.v, acc1, 0, 0, 0);
        } else {
            f32x16 q0, q1;
            q0 = __builtin_amdgcn_mfma_f32_32x32x16_bf16(Ah.v, Xh0.v, zz, 0, 0, 0);
            q1 = __builtin_amdgcn_mfma_f32_32x32x16_bf16(Ah.v, Xh1.v, zz, 0, 0, 0);
            q0 = __builtin_amdgcn_mfma_f32_32x32x16_bf16(Al.v, Xh0.v, q0, 0, 0, 0);
            q1 = __builtin_amdgcn_mfma_f32_32x32x16_bf16(Al.v, Xh1.v, q1, 0, 0, 0);
            q0 = __builtin_amdgcn_mfma_f32_32x32x16_bf16(Ah.v, Xl0.v, q0, 0, 0, 0);
            q1 = __builtin_amdgcn_mfma_f32_32x32x16_bf16(Ah.v, Xl1.v, q1, 0, 0, 0);
            float d0 = 0.f, d1 = 0.f;
#pragma unroll
            for (int j = 0; j < 16; ++j) {
                d0 = fmaf(q0[j], ov0[j], d0);
                d1 = fmaf(q1[j], ov1[j], d1);
            }
            d0 += __shfl_xor(d0, 32);
            d1 += __shfl_xor(d1, 32);
            float e0 = __expf(d0 - 20.0f);
            float e1 = __expf(d1 - 20.0f);
            Z0 += e0; Z1 += e1;
#pragma unroll
            for (int j = 0; j < 16; ++j) {
                acc0[j] = fmaf(e0, q0[j], acc0[j]);
                acc1[j] = fmaf(e1, q1[j], acc1[j]);
            }
        }
    }

    // ---- 8-wave LDS merge (4 h-slices; b-halves disjoint) ----
    const int b0 = bp * 64 + lo5, b1 = b0 + 32;
    __syncthreads();
#pragma unroll
    for (int j = 0; j < 16; ++j) {
        int orow = (j & 3) + 8 * (j >> 2) + 4 * hi1;
        lds[h * 4096 + b0 * 32 + (orow ^ lo5)] = acc0[j];
        lds[h * 4096 + b1 * 32 + (orow ^ lo5)] = acc1[j];
    }
    __syncthreads();
    float* po = ps + (size_t)(c * NCHK + rch) * 4096;
    for (int idx = t; idx < 4096; idx += 512) {
        int b = idx >> 5, o = idx & 31;
        float s = 0.f;
#pragma unroll
        for (int hh = 0; hh < 4; ++hh)
            s += lds[hh * 4096 + b * 32 + (o ^ (b & 31))];
        po[idx] = s;
    }
    if (MODE == 1) {
        __syncthreads();
        if (l < 32) {
            lds[h * 128 + bp * 64 + lo5] = Z0;
            lds[h * 128 + bp * 64 + 32 + lo5] = Z1;
        }
        __syncthreads();
        if (t < 128) {
            float z = lds[t] + lds[128 + t] + lds[256 + t] + lds[384 + t];
            pz[(size_t)(c * NCHK + rch) * 128 + t] = z;
        }
    }
}

// ------------------------------------------------------------------
// msq: merge chunk partials -> s, squash over batch, update oacc / out.
// MODE 0: uniform (s = sum/1152), oacc = squash. 1: oacc += squash. 2: out.
// Grid (10 c, 4 o-groups), 256 thr: t = o_off(8) x b_lo(32)
// ------------------------------------------------------------------
template<int MODE>
__global__ __launch_bounds__(256) void msq_k(const float* __restrict__ part_s,
                                             const float* __restrict__ pZ,
                                             float* __restrict__ oacc,
                                             float* __restrict__ dout)
{
    const int c = blockIdx.x, og = blockIdx.y;
    const int t = threadIdx.x;
    const int o_off = t & 7, b_lo = t >> 3;
    const int o = og * 8 + o_off;

    float sv[4];
    float pn = 0.f;
#pragma unroll
    for (int k = 0; k < 4; ++k) {
        int bb = b_lo + 32 * k;
        float s = 0.f;
#pragma unroll
        for (int ch = 0; ch < NCHK; ++ch)
            s += part_s[(((size_t)c * NCHK + ch) * NB + bb) * 32 + o];
        if (MODE == 0) {
            sv[k] = s * (1.0f / 1152.0f);
        } else {
            float z = 0.f;
#pragma unroll
            for (int ch = 0; ch < NCHK; ++ch)
                z += pZ[((size_t)c * NCHK + ch) * NB + bb];
            sv[k] = s / z;
        }
        pn = fmaf(sv[k], sv[k], pn);
    }
    __shared__ float red[256];
    __shared__ float fsh[8];
    red[t] = pn;
    __syncthreads();
    if (t < 8) {
        float n2 = 0.f;
#pragma unroll
        for (int j = 0; j < 32; ++j) n2 += red[t + 8 * j];
        fsh[t] = sqrtf(n2) / (1.0f + n2);   // (n2/(1+n2))/sqrt(n2)
    }
    __syncthreads();
    float f = fsh[o_off];
#pragma unroll
    for (int k = 0; k < 4; ++k) {
        int bb = b_lo + 32 * k;
        float v = sv[k] * f;
        size_t idx = ((size_t)c * NB + bb) * 32 + o;
        if (MODE == 0) oacc[idx] = v;
        if (MODE == 1) oacc[idx] += v;
        if (MODE == 2) dout[idx] = v;
    }
}

// ------------------------------------------------------------------
extern "C" void kernel_launch(void* const* d_in, const int* in_sizes, int n_in,
                              void* d_out, int out_size, void* d_ws, size_t ws_size,
                              hipStream_t stream)
{
    (void)in_sizes; (void)n_in; (void)out_size; (void)ws_size;
    const float* x = (const float*)d_in[0];
    const float* W = (const float*)d_in[1];
    float* wsf  = (float*)d_ws;
    float* outf = (float*)d_out;

    // ws layout (float units):
    // xT 2,359,296 | ps 983,040 | pz 30,720 | oacc 40,960  (~13.7 MB total)
    float* xT   = wsf;
    float* ps   = xT + (size_t)NR * 16 * NB;
    float* pz   = ps + (size_t)NC * NCHK * NB * 32;
    float* oacc = pz + (size_t)NC * NCHK * NB;

    dim3 mg(NC, 4);
    // iter 0: uniform weights; blocks emit coalesced xT (distributed by c)
    pass_x<0><<<240, 512, 0, stream>>>(x, W, xT, nullptr, ps, pz);
    msq_k<0><<<mg, 256, 0, stream>>>(ps, pz, oacc, nullptr);
    // iter 1: softmax(pred . out0), coalesced xT reads
    pass_x<1><<<240, 512, 0, stream>>>(x, W, xT, oacc, ps, pz);
    msq_k<1><<<mg, 256, 0, stream>>>(ps, pz, oacc, nullptr);
    // iter 2: softmax(pred . (out0+out1)) -> d_out
    pass_x<1><<<240, 512, 0, stream>>>(x, W, xT, oacc, ps, pz);
    msq_k<2><<<mg, 256, 0, stream>>>(ps, pz, oacc, outf);
}